// Round 9
// baseline (566.433 us; speedup 1.0000x reference)
//
#include <hip/hip_runtime.h>

#define B_ 4
#define N_ 2048
#define D_ 2048

typedef __bf16 bf16x8 __attribute__((ext_vector_type(8)));
typedef float  f32x4  __attribute__((ext_vector_type(4)));
typedef float  f32x16 __attribute__((ext_vector_type(16)));

__device__ __forceinline__ ushort f2bf(float x) {
  union { float f; unsigned u; } c; c.f = x;
  unsigned u = c.u;
  u += 0x7fffu + ((u >> 16) & 1u);   // RNE
  return (ushort)(u >> 16);
}

// async global->LDS, 16B per lane; lds base must be wave-uniform (HW adds lane*16)
__device__ __forceinline__ void gld16(ushort* lds, const ushort* g) {
  __builtin_amdgcn_global_load_lds(
      (const __attribute__((address_space(1))) void*)g,
      (__attribute__((address_space(3))) void*)lds, 16, 0, 0);
}

// ---------------- fused prep kernel ----------------
// roles by blockIdx.x:
//   [0,8192)      : cn = l2norm(data) bf16; catA[:, :D] = bf16(data)
//   [8192,16384)  : posenc pairs (sin,cos share angle) -> pe
//   [16384,20480) : weT = bf16(W_exp[1:,:]^T)   (D x D)
//   [20480,28672) : wmT = bf16(W_merge^T)       (D x 2D out)
#define PREP_BLOCKS 28672

__device__ __forceinline__ void do_transpose(const float* __restrict__ in,
                                             ushort* __restrict__ out,
                                             int R, int C, int bx, int byy, int tid) {
  __shared__ float t[32][33];
  const int c0 = bx * 32, r0 = byy * 32;
  const int tx = tid & 31, ty = tid >> 5;   // (32,8)
  #pragma unroll
  for (int i = 0; i < 32; i += 8) t[ty + i][tx] = in[(long)(r0 + ty + i) * C + c0 + tx];
  __syncthreads();
  #pragma unroll
  for (int i = 0; i < 32; i += 8) out[(long)(c0 + ty + i) * R + r0 + tx] = f2bf(t[tx][ty + i]);
}

__global__ __launch_bounds__(256) void prep_all(
    const float* __restrict__ data, ushort* __restrict__ cn, ushort* __restrict__ catA,
    ushort* __restrict__ pe, const float* __restrict__ W_exp, ushort* __restrict__ weT,
    const float* __restrict__ W_merge, ushort* __restrict__ wmT) {
  const int b = blockIdx.x;
  const int tid = threadIdx.x;

  if (b < 8192) {
    // ---- cn / catA role ----
    const int row = b;                         // 0..B*N-1
    const long base = (long)row * D_;
    const float4* r4 = (const float4*)(data + base);
    float4 u0 = r4[tid * 2], u1 = r4[tid * 2 + 1];
    float s = u0.x*u0.x + u0.y*u0.y + u0.z*u0.z + u0.w*u0.w
            + u1.x*u1.x + u1.y*u1.y + u1.z*u1.z + u1.w*u1.w;
    #pragma unroll
    for (int o = 32; o > 0; o >>= 1) s += __shfl_down(s, o);
    __shared__ float wsum[4];
    if ((tid & 63) == 0) wsum[tid >> 6] = s;
    __syncthreads();
    const float tot = wsum[0] + wsum[1] + wsum[2] + wsum[3];
    const float sc = rsqrtf(fmaxf(tot, 1e-12f));
    uint4 pc, pd;
    pc.x = (unsigned)f2bf(u0.x * sc) | ((unsigned)f2bf(u0.y * sc) << 16);
    pc.y = (unsigned)f2bf(u0.z * sc) | ((unsigned)f2bf(u0.w * sc) << 16);
    pc.z = (unsigned)f2bf(u1.x * sc) | ((unsigned)f2bf(u1.y * sc) << 16);
    pc.w = (unsigned)f2bf(u1.z * sc) | ((unsigned)f2bf(u1.w * sc) << 16);
    pd.x = (unsigned)f2bf(u0.x) | ((unsigned)f2bf(u0.y) << 16);
    pd.y = (unsigned)f2bf(u0.z) | ((unsigned)f2bf(u0.w) << 16);
    pd.z = (unsigned)f2bf(u1.x) | ((unsigned)f2bf(u1.y) << 16);
    pd.w = (unsigned)f2bf(u1.z) | ((unsigned)f2bf(u1.w) << 16);
    *(uint4*)(cn + base + tid * 8) = pc;
    *(uint4*)(catA + (long)row * (2 * D_) + tid * 8) = pd;
  } else if (b < 16384) {
    // ---- posenc role: one thread per (sin,cos) pair ----
    const int id = (b - 8192) * 256 + tid;     // 0..N*D/2-1
    const int n = id >> 10;                    // D/2 = 1024 pairs per row
    const int dp = id & 1023;
    const float e = (float)dp * (1.0f / 1024.0f);
    const float rate = __expf(e * -9.210340371976184f);   // 10000^-e
    const float ang = (float)n * rate;
    float rev = ang * 0.15915494309189535f;
    rev -= floorf(rev);
    const float ar = rev * 6.283185307179586f;
    const float sv = __sinf(ar);
    const float cv = __cosf(ar);
    *(unsigned*)(pe + (long)n * D_ + 2 * dp) =
        (unsigned)f2bf(sv) | ((unsigned)f2bf(cv) << 16);
  } else if (b < 20480) {
    const int blk = b - 16384;                 // 4096 blocks: 64x64 tiles
    do_transpose(W_exp + D_, weT, D_, D_, blk & 63, blk >> 6, tid);
  } else {
    const int blk = b - 20480;                 // 8192 blocks: 64x128 tiles
    do_transpose(W_merge, wmT, 2 * D_, D_, blk & 63, blk >> 6, tid);
  }
}

// ============ 256^2 8-phase NT GEMM — 32x32x16 MFMA, read-hoisted ============
// Same schedule skeleton as before (stage placement / vmcnt / barriers unchanged),
// but phases march over four 32-row m-groups (8 MFMA of 32x32x16 each) instead of
// eight 16-row pairs. -17% MFMA cycles (2495 vs 2176 TF ceiling).
// Fragment layouts: A/B lane l: row|col = l&31, k = (l>>5)*8+e.
// C/D [m74/m101]: col = lane&31, row = (reg&3) + 8*(reg>>2) + 4*(lane>>5).

__device__ __forceinline__ void stage_half(ushort* d, const ushort* s, int K) {
  gld16(d, s);
  gld16(d + 4096, s + (long)64 * K);
}

// A-frags for m-group MG: 4 k-subtiles (k = t*16 + (l>>5)*8)
template <int MG>
__device__ __forceinline__ void rd_a32(const ushort* __restrict__ T, int aBase,
                                       const int (&off)[4], bf16x8 (&af)[4]) {
  af[0] = *(const bf16x8*)&T[aBase + MG * 2048 + off[0]];
  af[1] = *(const bf16x8*)&T[aBase + MG * 2048 + off[1]];
  af[2] = *(const bf16x8*)&T[aBase + MG * 2048 + off[2]];
  af[3] = *(const bf16x8*)&T[aBase + MG * 2048 + off[3]];
}

// B-frags: 2 col-groups x 4 k-subtiles
__device__ __forceinline__ void rd_b32(const ushort* __restrict__ T, int bBase,
                                       const int (&off)[4], bf16x8 (&bf)[2][4]) {
  #pragma unroll
  for (int j = 0; j < 2; j++)
    #pragma unroll
    for (int t = 0; t < 4; t++)
      bf[j][t] = *(const bf16x8*)&T[bBase + j * 2048 + off[t]];
}

template <int MG>
__device__ __forceinline__ void mfma8(const bf16x8 (&af)[4], const bf16x8 (&bf)[2][4],
                                      f32x16 (&acc)[4][2]) {
  #pragma unroll
  for (int t = 0; t < 4; t++)          // ascending k
    #pragma unroll
    for (int j = 0; j < 2; j++)
      acc[MG][j] = __builtin_amdgcn_mfma_f32_32x32x16_bf16(
          af[t], bf[j][t], acc[MG][j], 0, 0, 0);
}

#define W_VM4   asm volatile("s_waitcnt vmcnt(4)" ::: "memory")
#define W_VM0   asm volatile("s_waitcnt vmcnt(0)" ::: "memory")
#define SBAR    asm volatile("s_barrier" ::: "memory")
#define PRIO1   __builtin_amdgcn_s_setprio(1)
#define PRIO0   __builtin_amdgcn_s_setprio(0)

// MODE 1: bf16 store | MODE 2: softplus(acc + csum*w0 + bexp) bf16 at col+colOff
// MODE 3: fp32 store | MODE 4: relu -> bf16 store + row-sum atomics into csum
template <int MODE>
__global__ __launch_bounds__(512, 2) void gemm8(
    const ushort* __restrict__ Ag, const ushort* __restrict__ Bg, void* __restrict__ Cg,
    int K, long sA, long sB, long sC, int ldc, int colOff,
    float* __restrict__ csum, const float* __restrict__ w0,
    const float* __restrict__ bexp) {
  extern __shared__ ushort lds[];   // [A0 16K | A1 16K | B0 16K | B1 16K] ushorts

  // XCD swizzle: lin%8 = "XCD" (round-robin assumption); each owns (z, y-half)
  const int lin = blockIdx.x + (blockIdx.y << 3) + (blockIdx.z << 6);
  const int xcd = lin & 7, m_ = lin >> 3;
  const int bz = xcd >> 1;
  const int by = ((xcd & 1) << 2) + (m_ >> 3);
  const int bx = m_ & 7;

  const ushort* A  = Ag + (long)bz * sA + (long)(bx << 8) * K;
  const ushort* Bp = Bg + (long)bz * sB + (long)(by << 8) * K;

  const int tid = threadIdx.x;
  // staging: thread covers linear half-tile bytes tid*16; global col pre-swizzled so
  // linear LDS holds the XOR-swizzled layout: LDS[r*64 + c] = G[r][c ^ ((r&7)<<3)]
  const int sr = tid >> 3;                         // row within half
  const int sc = ((tid & 7) ^ (sr & 7)) << 3;      // ushort col, XOR-swizzled
  const ushort* aS = A + (long)sr * K + sc;
  const ushort* bS = Bp + (long)sr * K + sc;
  const int wOff = (tid >> 6) << 9;                // wave-uniform LDS offset (ushorts)
  ushort* const stA0 = lds + wOff;
  ushort* const stA1 = lds + 16384 + wOff;
  ushort* const stB0 = lds + 32768 + wOff;
  ushort* const stB1 = lds + 49152 + wOff;
  const ushort* const TA0 = lds;          const ushort* const TA1 = lds + 16384;
  const ushort* const TB0 = lds + 32768;  const ushort* const TB1 = lds + 49152;

  auto stg = [&](ushort* base, const ushort* src, int T, int H) {
    stage_half(base + (H << 13), src + (long)(H << 7) * K + ((long)T << 6), K);
  };

  // fragment read offsets (swizzled): lane l reads row (base + l&31), k = t*16+(l>>5)*8
  const int L = tid & 63, wid = tid >> 6;
  const int wr = wid >> 2, wc = wid & 3;
  const int l31 = L & 31, hi = L >> 5;
  const int sx = (l31 & 7) << 3;
  const int c0 = hi << 3;
  int off[4];
  #pragma unroll
  for (int t = 0; t < 4; t++) off[t] = (((t << 4) | c0) ^ sx);
  const int aBase = ((wr << 7) + l31) * 64;
  const int bBase = ((wc << 6) + l31) * 64;

  f32x16 acc[4][2] = {};
  bf16x8 af[4], bf[2][4];

  const int NT = K >> 6, NTI = NT >> 1;

  // prologue: tile0 -> buf0 (8 loads), B(tile1) -> buf1 (4), A1h0(tile1) (2) = 14 issues
  stg(stB0, bS, 0, 0); stg(stB0, bS, 0, 1); stg(stA0, aS, 0, 0); stg(stA0, aS, 0, 1);
  stg(stB1, bS, 1, 0); stg(stB1, bS, 1, 1);
  stg(stA1, aS, 1, 0);
  asm volatile("s_waitcnt vmcnt(6)" ::: "memory");   // tile0 fully landed
  SBAR;
  // pre-reads for ph1 (B buf0 + A MG0)
  rd_b32(TB0, bBase, off, bf);
  rd_a32<0>(TA0, aBase, off, af);

  for (int it = 0; it < NTI; ++it) {
    const int t1 = 2 * it + 1, t2 = 2 * it + 2, t3 = 2 * it + 3;
    const bool more = (it + 1 < NTI);

    // ---- ph1: MFMA MG0 (buf0) ----
    stg(stA1, aS, t1, 1);                 // A1h1(T1)
    PRIO1; mfma8<0>(af, bf, acc); PRIO0;
    rd_a32<1>(TA0, aBase, off, af);
    SBAR;
    // ---- ph2: MFMA MG1 ----
    if (more) stg(stB0, bS, t2, 0);       // B0h0(T2)
    PRIO1; mfma8<1>(af, bf, acc); PRIO0;
    rd_a32<2>(TA0, aBase, off, af);
    SBAR;
    // ---- ph3: MFMA MG2 ----
    if (more) stg(stB0, bS, t2, 1);       // B0h1(T2)
    PRIO1; mfma8<2>(af, bf, acc); PRIO0;
    rd_a32<3>(TA0, aBase, off, af);
    SBAR;
    // ---- ph4: MFMA MG3; then switch to buf1 reads ----
    if (more) { W_VM4; } else { W_VM0; }  // force tile T1 (buf1) landed
    SBAR;                                 // all waves' T1 slices visible
    PRIO1; mfma8<3>(af, bf, acc); PRIO0;
    rd_b32(TB1, bBase, off, bf);
    rd_a32<0>(TA1, aBase, off, af);
    SBAR;
    // ---- ph5: MFMA MG0 (buf1) ----
    if (more) stg(stA0, aS, t2, 0);       // A0h0(T2)
    PRIO1; mfma8<0>(af, bf, acc); PRIO0;
    rd_a32<1>(TA1, aBase, off, af);
    SBAR;
    // ---- ph6: MFMA MG1 ----
    if (more) stg(stA0, aS, t2, 1);       // A0h1(T2)
    PRIO1; mfma8<1>(af, bf, acc); PRIO0;
    rd_a32<2>(TA1, aBase, off, af);
    SBAR;
    // ---- ph7: MFMA MG2 ----
    if (more) stg(stB1, bS, t3, 0);       // B1h0(T3)
    PRIO1; mfma8<2>(af, bf, acc); PRIO0;
    rd_a32<3>(TA1, aBase, off, af);
    SBAR;
    // ---- ph8: MFMA MG3; then switch to buf0 (tile T2) reads ----
    if (more) stg(stB1, bS, t3, 1);       // B1h1(T3)
    if (more) { W_VM4; }                  // force tile T2 (buf0) landed
    SBAR;
    PRIO1; mfma8<3>(af, bf, acc); PRIO0;
    if (more) {
      rd_b32(TB0, bBase, off, bf);
      rd_a32<0>(TA0, aBase, off, af);
      stg(stA1, aS, t3, 0);               // A1h0(T3) — lead for next iter's ph4
    }
    SBAR;
  }

  // ---------------- vectorized epilogue (per-wave private LDS patch) ----------------
  // C/D: col = l&31 (+ j*32), row = (reg&3) + 8*(reg>>2) + 4*hi (+ MG*32)
  const int rowB0 = (bx << 8) + (wr << 7);
  const int colB0 = (by << 8) + (wc << 6);
  const int r_ = L >> 1, half = L & 1;

  if (MODE == 3) {
    // per-wave 32x64 fp32 patch, pitch 68 floats (272B rows, 16B-aligned)
    float* eT = (float*)lds + (size_t)wid * 2176;
    float* Cb = (float*)Cg + (long)bz * sC;
    #pragma unroll
    for (int mg = 0; mg < 4; mg++) {
      #pragma unroll
      for (int j = 0; j < 2; j++)
        #pragma unroll
        for (int reg = 0; reg < 16; reg++) {
          const int prow = (reg & 3) + 8 * (reg >> 2) + 4 * hi;
          eT[prow * 68 + j * 32 + l31] = acc[mg][j][reg];
        }
      #pragma unroll
      for (int q = 0; q < 8; q++) {
        const f32x4 v = *(const f32x4*)&eT[r_ * 68 + half * 32 + q * 4];
        const long row = rowB0 + mg * 32 + r_;
        *(f32x4*)&Cb[row * ldc + colB0 + half * 32 + q * 4] = v;
      }
    }
  } else {
    // per-wave 32x64 bf16 patch, pitch 72 ushorts (144B rows, 16B-aligned)
    ushort* eT = lds + (size_t)wid * 2304;
    ushort* Cb = (ushort*)Cg + (long)bz * sC;
    float w0v[2], bev[2];
    if (MODE == 2) {
      #pragma unroll
      for (int j = 0; j < 2; j++) {
        w0v[j] = w0[colB0 + j * 32 + l31];
        bev[j] = bexp[colB0 + j * 32 + l31];
      }
    }
    #pragma unroll
    for (int mg = 0; mg < 4; mg++) {
      #pragma unroll
      for (int reg = 0; reg < 16; reg++) {
        const int prow = (reg & 3) + 8 * (reg >> 2) + 4 * hi;
        float x0 = acc[mg][0][reg], x1 = acc[mg][1][reg];
        if (MODE == 2) {
          const float cv = csum[(long)bz * N_ + rowB0 + mg * 32 + prow];
          x0 = x0 + cv * w0v[0] + bev[0];
          x1 = x1 + cv * w0v[1] + bev[1];
          x0 = fmaxf(x0, 0.f) + log1pf(expf(-fabsf(x0)));
          x1 = fmaxf(x1, 0.f) + log1pf(expf(-fabsf(x1)));
        }
        if (MODE == 4) {
          x0 = fmaxf(x0, 0.f);
          x1 = fmaxf(x1, 0.f);
          float s = x0 + x1;   // this lane: 2 cols of row prow
          s += __shfl_xor(s, 1); s += __shfl_xor(s, 2);
          s += __shfl_xor(s, 4); s += __shfl_xor(s, 8); s += __shfl_xor(s, 16);
          if (l31 == 0)
            atomicAdd(&csum[(long)bz * N_ + rowB0 + mg * 32 + prow], s);
        }
        eT[prow * 72 + l31] = f2bf(x0);
        eT[prow * 72 + 32 + l31] = f2bf(x1);
      }
      #pragma unroll
      for (int q = 0; q < 4; q++) {
        const uint4 v = *(const uint4*)&eT[r_ * 72 + half * 32 + q * 8];
        const long row = rowB0 + mg * 32 + r_;
        *(uint4*)&Cb[row * ldc + colOff + colB0 + half * 32 + q * 8] = v;
      }
    }
  }
}

// ---------------- launch ----------------
extern "C" void kernel_launch(void* const* d_in, const int* in_sizes, int n_in,
                              void* d_out, int out_size, void* d_ws, size_t ws_size,
                              hipStream_t stream) {
  const float* data    = (const float*)d_in[0];
  const float* W_exp   = (const float*)d_in[1];
  const float* b_exp   = (const float*)d_in[2];
  const float* W_merge = (const float*)d_in[3];

  char* ws = (char*)d_ws;
  const size_t MB = 1024 * 1024;
  ushort* cnv  = (ushort*)(ws);             // 32MB: cn, then reused as v_out
  ushort* sim  = (ushort*)(ws + 32 * MB);   // 32MB
  ushort* pe   = (ushort*)(ws + 64 * MB);   // 8MB
  ushort* weT  = (ushort*)(ws + 72 * MB);   // 8MB:  W_exp[1:,:]^T
  ushort* wmT  = (ushort*)(ws + 80 * MB);   // 16MB: W_merge^T
  ushort* catA = (ushort*)(ws + 96 * MB);   // 64MB: [data | counter] bf16
  float*  csum = (float*)(ws + 160 * MB);   // 128KB

  static bool attrs_set = false;
  if (!attrs_set) {
    (void)hipFuncSetAttribute((const void*)gemm8<1>, hipFuncAttributeMaxDynamicSharedMemorySize, 131072);
    (void)hipFuncSetAttribute((const void*)gemm8<2>, hipFuncAttributeMaxDynamicSharedMemorySize, 131072);
    (void)hipFuncSetAttribute((const void*)gemm8<3>, hipFuncAttributeMaxDynamicSharedMemorySize, 131072);
    (void)hipFuncSetAttribute((const void*)gemm8<4>, hipFuncAttributeMaxDynamicSharedMemorySize, 131072);
    attrs_set = true;
  }

  hipMemsetAsync(csum, 0, (size_t)B_ * N_ * sizeof(float), stream);
  prep_all<<<PREP_BLOCKS, 256, 0, stream>>>(data, cnv, catA, pe, W_exp, weT, W_merge, wmT);

  dim3 g8(N_ / 256, N_ / 256, B_);
  // G1: sim = relu(cn cn^T) full grid (NT: B operand = cn rows), row-sums -> csum
  gemm8<4><<<g8, 512, 131072, stream>>>(cnv, cnv, sim, N_, (long)N_ * D_, (long)N_ * D_,
                                        (long)N_ * N_, N_, 0, csum, nullptr, nullptr);
  // G2: v_out = pe @ sim  (sim symmetric -> NT form), into cnv region (cn is dead)
  gemm8<1><<<g8, 512, 131072, stream>>>(pe, sim, cnv, N_, 0, (long)N_ * N_,
                                        (long)N_ * N_, N_, 0, nullptr, nullptr, nullptr);
  // G3: catA[:, D:] = softplus(v_out @ W_exp[1:] + csum*w0 + b_exp)
  gemm8<2><<<g8, 512, 131072, stream>>>(cnv, weT, catA, N_, (long)N_ * N_, 0,
                                        (long)N_ * 2 * D_, 2 * D_, D_, csum, W_exp, b_exp);
  // G4: out = catA @ W_merge
  gemm8<3><<<g8, 512, 131072, stream>>>(catA, wmT, d_out, 2 * D_, (long)N_ * 2 * D_, 0,
                                        (long)N_ * D_, D_, 0, nullptr, nullptr, nullptr);
}